// Round 17
// baseline (50.663 us; speedup 1.0000x reference)
//
#include <hip/hip_runtime.h>

#define HID 64
#define NTOK 66          // VOCAB_SIZE + 2
#define SEQ 64
#define WIN0 55          // SEQ_LEN - 1 - MEMORY_SLOTS
#define NW 8
#define LDS_STRIDE 72    // ushorts per table row (144B)
#define ITERS 8          // iterations per block (rows/block = 1024, grid = 512)
#define BLOCK 512        // 8 waves
#define ROWS_PER_ITER 128 // 8 waves x 16 rows

typedef _Float16 half8 __attribute__((ext_vector_type(8)));
typedef unsigned short ushort8v __attribute__((ext_vector_type(8)));
typedef float float4v __attribute__((ext_vector_type(4)));

static __device__ __forceinline__ unsigned short f2h(float f) {
    _Float16 h = (_Float16)f;
    union { _Float16 h; unsigned short u; } v; v.h = h;
    return v.u;
}

// Kernel 1: tables T1[t][n] = b1[n] + sum_k emb[t][k]*W1[n][k]
//           T2[t][n] = 0.125 * sum_k emb[t][k]*W1[n][64+k]
// stored F16 in ws: [2][66][64]
__global__ void build_tables(const float* __restrict__ embed,
                             const float* __restrict__ W1,
                             const float* __restrict__ b1,
                             unsigned short* __restrict__ tbl) {
    int b = blockIdx.x;      // 0..131
    int tb = b & 1;
    int t  = b >> 1;
    int n  = threadIdx.x;    // 0..63
    float acc = tb ? 0.0f : b1[n];
    const float* er = embed + t * HID;
    const float* wr = W1 + n * (2 * HID) + tb * HID;
#pragma unroll 8
    for (int k = 0; k < HID; ++k) acc += er[k] * wr[k];
    if (tb) acc *= 0.125f;
    tbl[tb * (NTOK * HID) + t * HID + n] = f2h(acc);
}

// Kernel 2: logits^T = W2 (A-op) x h^T (B-op) via mfma_f32_16x16x32_f16.
// ZERO-LOAD LOOP: all 72 token indices for the 8 iterations are loaded in
// the prologue (before any store exists in the VMEM FIFO). gfx9 vmcnt
// retires IN ORDER, so a load queued behind prior-iteration stores only
// becomes visible after those stores drain to L2 -- the suspected ~300-500
// cy/iter stall. With no loads in the loop there are no vmcnt waits at
// all; stores are fire-and-forget. Depth-2 rotating gather (g0/g1 reissued
// with iter t+1's tokens), interleaved dual sum chains, stores spread
// per-nt. Register census ~220 <= 256 budget at (512,2).
__global__ __launch_bounds__(BLOCK, 2) void fused_forward(
    const int* __restrict__ seqs,
    const int* __restrict__ qtok,
    const float* __restrict__ W2,
    const float* __restrict__ b2,
    const unsigned short* __restrict__ tbl,
    float* __restrict__ out)
{
    __shared__ unsigned short T_lds[2 * NTOK * LDS_STRIDE]; // 19008 B

    int tid  = threadIdx.x;
    int wv   = tid >> 6;        // 0..7
    int l    = tid & 63;
    int lrow = l & 15;          // W2 row within n-tile / batch row within tile
    int lg   = l >> 4;
    int lk8  = lg * 8;          // k offset within 32-wide K chunk

    int row0 = blockIdx.x * (ITERS * ROWS_PER_ITER) + wv * 16 + lrow;

    // ---- (1) ALL token loads up front: nothing ahead of them in the FIFO,
    // latency hidden under W2 fragment loads + LDS fill + barrier. All
    // indices below are compile-time literals (fully unrolled). ----
    int qT[ITERS];
    int wT[ITERS][NW];
#pragma unroll
    for (int t = 0; t < ITERS; ++t) {
        int row_ = row0 + t * ROWS_PER_ITER;
        qT[t] = qtok[row_];
        const int* sp_ = seqs + row_ * SEQ + WIN0;
#pragma unroll
        for (int j = 0; j < NW; ++j) wT[t][j] = sp_[j];
    }

    // ---- (2) W2 A-fragments in registers (whole 64x64, f16) + b2 float4 ----
    half8   wfrag[4][2];
    float4v b2v[4];
#pragma unroll
    for (int nt = 0; nt < 4; ++nt) {
        b2v[nt] = *(const float4v*)(b2 + nt * 16 + lg * 4);
#pragma unroll
        for (int kc = 0; kc < 2; ++kc) {
            const float* wp = W2 + (nt * 16 + lrow) * HID + kc * 32 + lk8;
            half8 f;
#pragma unroll
            for (int j = 0; j < 8; ++j) f[j] = (_Float16)wp[j];
            wfrag[nt][kc] = f;
        }
    }

    // ---- (3) fill LDS tables (16B chunks; row stride 144B) ----
    for (int i = tid; i < 2 * NTOK * (HID / 8); i += BLOCK) {
        int tbi = i / (NTOK * 8);
        int rem = i - tbi * (NTOK * 8);
        int t   = rem >> 3;
        int kq  = (rem & 7) << 3;
        *(ushort8v*)(T_lds + tbi * (NTOK * LDS_STRIDE) + t * LDS_STRIDE + kq) =
            *(const ushort8v*)(tbl + tbi * (NTOK * HID) + t * HID + kq);
    }
    __syncthreads();

    half8 g0[9], g1[9];         // stage buffers: chunk0 / chunk1 of current iter
    half8 a0, a1;

#define RD_T1(qq, koff) (*(const half8*)(T_lds + (qq) * LDS_STRIDE + (koff)))
#define RD_T2(ww, koff) (*(const half8*)(T_lds + NTOK * LDS_STRIDE + (ww) * LDS_STRIDE + (koff)))

// interleaved dual-chain consume + reissue with iter (t_+1)'s tokens
#define SUM2_REISSUE(t_) { \
    half8 s0_ = g0[8], s1_ = g1[8]; \
    g0[8] = RD_T1(qT[(t_) + 1], lk8); \
    g1[8] = RD_T1(qT[(t_) + 1], 32 + lk8); \
    _Pragma("unroll") \
    for (int j = 0; j < NW; ++j) { \
        s0_ += g0[j]; \
        g0[j] = RD_T2(wT[(t_) + 1][j], lk8); \
        s1_ += g1[j]; \
        g1[j] = RD_T2(wT[(t_) + 1][j], 32 + lk8); \
    } \
    half8 z_ = (half8)(_Float16)0; \
    a0 = __builtin_elementwise_max(s0_, z_); \
    a1 = __builtin_elementwise_max(s1_, z_); \
}

#define SUM2_FINAL { \
    half8 s0_ = g0[8], s1_ = g1[8]; \
    _Pragma("unroll") \
    for (int j = 0; j < NW; ++j) { s0_ += g0[j]; s1_ += g1[j]; } \
    half8 z_ = (half8)(_Float16)0; \
    a0 = __builtin_elementwise_max(s0_, z_); \
    a1 = __builtin_elementwise_max(s1_, z_); \
}

// both K-halves per nt, then store that nt immediately (stores spread)
#define MFMA_ST(t_) { \
    float* op = out + (size_t)(row0 + (t_) * ROWS_PER_ITER) * HID; \
    _Pragma("unroll") \
    for (int nt = 0; nt < 4; ++nt) { \
        float4v acc_ = __builtin_amdgcn_mfma_f32_16x16x32_f16(wfrag[nt][0], a0, b2v[nt], 0, 0, 0); \
        acc_ = __builtin_amdgcn_mfma_f32_16x16x32_f16(wfrag[nt][1], a1, acc_, 0, 0, 0); \
        *(float4v*)(op + nt * 16 + lg * 4) = acc_; \
    } \
}

#define ITER_MID(t_)  { SUM2_REISSUE(t_); MFMA_ST(t_); }
#define ITER_LAST(t_) { SUM2_FINAL;       MFMA_ST(t_); }

    // ---- (4) prologue gather for iter 0, then 8 zero-load iterations ----
    {
        g0[8] = RD_T1(qT[0], lk8);
        g1[8] = RD_T1(qT[0], 32 + lk8);
#pragma unroll
        for (int j = 0; j < NW; ++j) {
            g0[j] = RD_T2(wT[0][j], lk8);
            g1[j] = RD_T2(wT[0][j], 32 + lk8);
        }
    }

    ITER_MID(0);
    ITER_MID(1);
    ITER_MID(2);
    ITER_MID(3);
    ITER_MID(4);
    ITER_MID(5);
    ITER_MID(6);
    ITER_LAST(7);

#undef RD_T1
#undef RD_T2
#undef SUM2_REISSUE
#undef SUM2_FINAL
#undef MFMA_ST
#undef ITER_MID
#undef ITER_LAST
}

extern "C" void kernel_launch(void* const* d_in, const int* in_sizes, int n_in,
                              void* d_out, int out_size, void* d_ws, size_t ws_size,
                              hipStream_t stream) {
    const int*   seqs  = (const int*)d_in[0];
    const int*   qtok  = (const int*)d_in[1];
    const float* embed = (const float*)d_in[2];
    const float* W1    = (const float*)d_in[3];
    const float* b1    = (const float*)d_in[4];
    const float* W2    = (const float*)d_in[5];
    const float* b2    = (const float*)d_in[6];
    float* out = (float*)d_out;
    unsigned short* tbl = (unsigned short*)d_ws;

    int B = in_sizes[0] / SEQ;

    build_tables<<<NTOK * 2, HID, 0, stream>>>(embed, W1, b1, tbl);

    int grid = B / (ITERS * ROWS_PER_ITER);
    fused_forward<<<grid, BLOCK, 0, stream>>>(seqs, qtok, W2, b2, tbl, out);
}

// Round 18
// 50.100 us; speedup vs baseline: 1.0112x; 1.0112x over previous
//
#include <hip/hip_runtime.h>

#define HID 64
#define NTOK 66           // VOCAB_SIZE + 2
#define SEQ 64
#define WIN0 55           // SEQ_LEN - 1 - MEMORY_SLOTS
#define NW 8
#define LDS_STRIDE 72     // ushorts per table row (144B)
#define ITERS 8           // iterations per block (rows/block = 1024, grid = 512)
#define BLOCK 512         // 8 waves
#define ROWS_PER_ITER 128 // 8 waves x 16 rows
#define HOFF (2 * NTOK * LDS_STRIDE)  // ushort offset of h region
#define HSZ  (16 * LDS_STRIDE)        // h buffer: 16 rows/wave (ushorts)

typedef _Float16 half8 __attribute__((ext_vector_type(8)));
typedef unsigned short ushort8v __attribute__((ext_vector_type(8)));
typedef float float4v __attribute__((ext_vector_type(4)));

static __device__ __forceinline__ unsigned short f2h(float f) {
    _Float16 h = (_Float16)f;
    union { _Float16 h; unsigned short u; } v; v.h = h;
    return v.u;
}

// Kernel 1: tables T1[t][n] = b1[n] + sum_k emb[t][k]*W1[n][k]
//           T2[t][n] = 0.125 * sum_k emb[t][k]*W1[n][64+k]   (f16)
__global__ void build_tables(const float* __restrict__ embed,
                             const float* __restrict__ W1,
                             const float* __restrict__ b1,
                             unsigned short* __restrict__ tbl) {
    int b = blockIdx.x;      // 0..131
    int tb = b & 1;
    int t  = b >> 1;
    int n  = threadIdx.x;    // 0..63
    float acc = tb ? 0.0f : b1[n];
    const float* er = embed + t * HID;
    const float* wr = W1 + n * (2 * HID) + tb * HID;
#pragma unroll 8
    for (int k = 0; k < HID; ++k) acc += er[k] * wr[k];
    if (tb) acc *= 0.125f;
    tbl[tb * (NTOK * HID) + t * HID + n] = f2h(acc);
}

// Kernel 2: logits^T = W2 (A-op) x h^T (B-op) via mfma_f32_16x16x32_f16.
// COOPERATIVE CONFLICT-FREE GATHER: 8 lanes per output row, lane owns one
// 16B k-chunk. Gather read quad = (token + chunk) mod 8 -> every wave
// instruction covers all 32 banks UNIFORMLY regardless of token values
// (vs 16-random-rows-on-8-quads before: ~60% conflict overhead, 4.24M cy).
// h routed through per-wave double-buffered LDS (write uniform; fragment
// read 2-way aliased = free). No barrier: each wave reads only its own
// writes, DS pipe is in-order per wave. h-LDS IS the pipeline stage ->
// the 72-VGPR register stage arrays are gone. produce(t+1) then consume(t).
__global__ __launch_bounds__(BLOCK, 2) void fused_forward(
    const int* __restrict__ seqs,
    const int* __restrict__ qtok,
    const float* __restrict__ W2,
    const float* __restrict__ b2,
    const unsigned short* __restrict__ tbl,
    float* __restrict__ out)
{
    // tables 19008 B + h 8 waves x 2 bufs x 16 rows x 144 B = 36864 B
    __shared__ unsigned short T_lds[HOFF + 8 * 2 * HSZ];    // 55872 B

    int tid  = threadIdx.x;
    int wv   = tid >> 6;        // 0..7
    int l    = tid & 63;
    int lrow = l & 15;          // consume: batch row within wave tile
    int lg   = l >> 4;
    int lk8  = lg * 8;          // consume: k offset (ushorts)
    int rgrp = l >> 3;          // produce: row group 0..7
    int pchk = (l & 7) * 8;     // produce: k-chunk offset (ushorts)

    int blk0  = blockIdx.x * (ITERS * ROWS_PER_ITER);
    int crow0 = blk0 + wv * 16 + lrow;   // consume row base (+ t*128)
    int prow0 = blk0 + wv * 16 + rgrp;   // produce row base (+ t*128, +8 pass1)

    unsigned short* hb = T_lds + HOFF + wv * (2 * HSZ);

    int qA0, qA1, qB0, qB1;
    int wA0[NW], wA1[NW], wB0[NW], wB1[NW];

// tokens for this lane's 2 assigned produce-rows of iter t_
#define LOADT(s, t_) { \
    int pr_ = prow0 + (t_) * ROWS_PER_ITER; \
    q##s##0 = qtok[pr_]; \
    q##s##1 = qtok[pr_ + 8]; \
    const int* s0_ = seqs + pr_ * SEQ + WIN0; \
    const int* s1_ = seqs + (pr_ + 8) * SEQ + WIN0; \
    _Pragma("unroll") \
    for (int j = 0; j < NW; ++j) { w##s##0[j] = s0_[j]; w##s##1[j] = s1_[j]; } \
}

#define RD_T1(qq) (*(const half8*)(T_lds + (qq) * LDS_STRIDE + pchk))
#define RD_T2(ww) (*(const half8*)(T_lds + NTOK * LDS_STRIDE + (ww) * LDS_STRIDE + pchk))

// cooperative gather+sum+relu for 16 rows (2 passes of 8), write h to buf_
#define PRODUCE(s, buf_) { \
    half8 s0_ = RD_T1(q##s##0); \
    half8 s1_ = RD_T1(q##s##1); \
    _Pragma("unroll") \
    for (int j = 0; j < NW; ++j) { \
        s0_ += RD_T2(w##s##0[j]); \
        s1_ += RD_T2(w##s##1[j]); \
    } \
    half8 z_ = (half8)(_Float16)0; \
    s0_ = __builtin_elementwise_max(s0_, z_); \
    s1_ = __builtin_elementwise_max(s1_, z_); \
    *(half8*)(hb + (buf_) * HSZ + rgrp * LDS_STRIDE + pchk) = s0_; \
    *(half8*)(hb + (buf_) * HSZ + (rgrp + 8) * LDS_STRIDE + pchk) = s1_; \
}

// read B-fragments from h buf_, MFMA (bias in C), store
#define CONSUME(t_, buf_) { \
    half8 a0 = *(const half8*)(hb + (buf_) * HSZ + lrow * LDS_STRIDE + lk8); \
    half8 a1 = *(const half8*)(hb + (buf_) * HSZ + lrow * LDS_STRIDE + 32 + lk8); \
    float* op = out + (size_t)(crow0 + (t_) * ROWS_PER_ITER) * HID; \
    _Pragma("unroll") \
    for (int nt = 0; nt < 4; ++nt) { \
        float4v acc_ = __builtin_amdgcn_mfma_f32_16x16x32_f16(wfrag[nt][0], a0, b2v[nt], 0, 0, 0); \
        acc_ = __builtin_amdgcn_mfma_f32_16x16x32_f16(wfrag[nt][1], a1, acc_, 0, 0, 0); \
        *(float4v*)(op + nt * 16 + lg * 4) = acc_; \
    } \
}

    // ---- (1) iter 0/1 token loads: latency hides under W2+fill+barrier ----
    LOADT(A, 0);
    LOADT(B, 1);

    // ---- (2) W2 A-fragments in registers (whole 64x64, f16) + b2 float4 ----
    half8   wfrag[4][2];
    float4v b2v[4];
#pragma unroll
    for (int nt = 0; nt < 4; ++nt) {
        b2v[nt] = *(const float4v*)(b2 + nt * 16 + lg * 4);
#pragma unroll
        for (int kc = 0; kc < 2; ++kc) {
            const float* wp = W2 + (nt * 16 + lrow) * HID + kc * 32 + lk8;
            half8 f;
#pragma unroll
            for (int j = 0; j < 8; ++j) f[j] = (_Float16)wp[j];
            wfrag[nt][kc] = f;
        }
    }

    // ---- (3) fill LDS tables (16B chunks; row stride 144B) ----
    for (int i = tid; i < 2 * NTOK * (HID / 8); i += BLOCK) {
        int tbi = i / (NTOK * 8);
        int rem = i - tbi * (NTOK * 8);
        int t   = rem >> 3;
        int kq  = (rem & 7) << 3;
        *(ushort8v*)(T_lds + tbi * (NTOK * LDS_STRIDE) + t * LDS_STRIDE + kq) =
            *(const ushort8v*)(tbl + tbi * (NTOK * HID) + t * HID + kq);
    }
    __syncthreads();

    // ---- (4) produce(t+1) / consume(t) pipeline, h double-buffered ----
    PRODUCE(A, 0);              // h[0] -> buf0
    LOADT(A, 2);

    PRODUCE(B, 1); CONSUME(0, 0); LOADT(B, 3);
    PRODUCE(A, 0); CONSUME(1, 1); LOADT(A, 4);
    PRODUCE(B, 1); CONSUME(2, 0); LOADT(B, 5);
    PRODUCE(A, 0); CONSUME(3, 1); LOADT(A, 6);
    PRODUCE(B, 1); CONSUME(4, 0); LOADT(B, 7);
    PRODUCE(A, 0); CONSUME(5, 1);
    PRODUCE(B, 1); CONSUME(6, 0);
                   CONSUME(7, 1);

#undef LOADT
#undef RD_T1
#undef RD_T2
#undef PRODUCE
#undef CONSUME
}

extern "C" void kernel_launch(void* const* d_in, const int* in_sizes, int n_in,
                              void* d_out, int out_size, void* d_ws, size_t ws_size,
                              hipStream_t stream) {
    const int*   seqs  = (const int*)d_in[0];
    const int*   qtok  = (const int*)d_in[1];
    const float* embed = (const float*)d_in[2];
    const float* W1    = (const float*)d_in[3];
    const float* b1    = (const float*)d_in[4];
    const float* W2    = (const float*)d_in[5];
    const float* b2    = (const float*)d_in[6];
    float* out = (float*)d_out;
    unsigned short* tbl = (unsigned short*)d_ws;

    int B = in_sizes[0] / SEQ;

    build_tables<<<NTOK * 2, HID, 0, stream>>>(embed, W1, b1, tbl);

    int grid = B / (ITERS * ROWS_PER_ITER);
    fused_forward<<<grid, BLOCK, 0, stream>>>(seqs, qtok, W2, b2, tbl, out);
}

// Round 19
// 46.537 us; speedup vs baseline: 1.0887x; 1.0766x over previous
//
#include <hip/hip_runtime.h>

#define HID 64
#define NTOK 66          // VOCAB_SIZE + 2
#define SEQ 64
#define WIN0 55          // SEQ_LEN - 1 - MEMORY_SLOTS
#define NW 8
#define LDS_STRIDE 72    // ushorts per table row (144B)
#define ITERS 16         // iterations per block (rows/block = 2048, grid = 256)
#define BLOCK 512        // 8 waves
#define ROWS_PER_ITER 128 // 8 waves x 16 rows

typedef _Float16 half8 __attribute__((ext_vector_type(8)));
typedef unsigned short ushort8v __attribute__((ext_vector_type(8)));
typedef float float4v __attribute__((ext_vector_type(4)));

static __device__ __forceinline__ unsigned short f2h(float f) {
    _Float16 h = (_Float16)f;
    union { _Float16 h; unsigned short u; } v; v.h = h;
    return v.u;
}

// Kernel 1: tables T1[t][n] = b1[n] + sum_k emb[t][k]*W1[n][k]
//           T2[t][n] = 0.125 * sum_k emb[t][k]*W1[n][64+k]   (f16)
__global__ void build_tables(const float* __restrict__ embed,
                             const float* __restrict__ W1,
                             const float* __restrict__ b1,
                             unsigned short* __restrict__ tbl) {
    int b = blockIdx.x;      // 0..131
    int tb = b & 1;
    int t  = b >> 1;
    int n  = threadIdx.x;    // 0..63
    float acc = tb ? 0.0f : b1[n];
    const float* er = embed + t * HID;
    const float* wr = W1 + n * (2 * HID) + tb * HID;
#pragma unroll 8
    for (int k = 0; k < HID; ++k) acc += er[k] * wr[k];
    if (tb) acc *= 0.125f;
    tbl[tb * (NTOK * HID) + t * HID + n] = f2h(acc);
}

// Kernel 2: logits^T = W2 (A-op) x h^T (B-op) via mfma_f32_16x16x32_f16.
// R16 structure (best, 47.5us) with grid=256 = EXACTLY 1 block/CU:
// prologue (table fill + W2 frags + barrier) paid once per CU instead of
// twice; fill traffic halves; zero dispatch imbalance (256/8 XCDs = 32/XCD).
// Depth-2 rotating gather: g0/g1 hold iter t's two chunks; each consume
// reissues the slot with iter t+1's tokens (full-iteration read shadow).
// NOTE (falsified levers, do not revisit): nontemporal hints (R10 -43%),
// global pair-table gather (R13, evicted by own store stream), s_sleep
// convoy stagger (R14 null), zero-load loop (R17 -3.2), cooperative
// conflict-free gather (R18: SQ_LDS_BANK_CONFLICT is intrinsic b128
// multi-pass cost, not avoidable collisions).
__global__ __launch_bounds__(BLOCK, 2) void fused_forward(
    const int* __restrict__ seqs,
    const int* __restrict__ qtok,
    const float* __restrict__ W2,
    const float* __restrict__ b2,
    const unsigned short* __restrict__ tbl,
    float* __restrict__ out)
{
    __shared__ unsigned short T_lds[2 * NTOK * LDS_STRIDE]; // 19008 B

    int tid  = threadIdx.x;
    int wv   = tid >> 6;        // 0..7
    int l    = tid & 63;
    int lrow = l & 15;          // W2 row within n-tile / batch row within tile
    int lg   = l >> 4;
    int lk8  = lg * 8;          // k offset within 32-wide K chunk

    int row0 = blockIdx.x * (ITERS * ROWS_PER_ITER) + wv * 16 + lrow;

    int qA, qB;
    int wA[NW], wB[NW];
    half8  g0[9], g1[9];        // stage buffers: chunk0 / chunk1 of current iter
    half8  a0, a1;
    float4v acc4[4];

// scalar token loads (proven-clean HBM traffic)
#define LOADT(s, t_) { \
    int row_ = row0 + (t_) * ROWS_PER_ITER; \
    q##s = qtok[row_]; \
    const int* sp_ = seqs + row_ * SEQ + WIN0; \
    _Pragma("unroll") \
    for (int j = 0; j < NW; ++j) w##s[j] = sp_[j]; \
}

// fill one stage buffer (prologue only)
#define GATHER_ALL(g, qq, ww, k0c) { \
    (g)[8] = *(const half8*)(T_lds + (qq) * LDS_STRIDE + (k0c)); \
    _Pragma("unroll") \
    for (int j = 0; j < NW; ++j) \
        (g)[j] = *(const half8*)(T_lds + NTOK * LDS_STRIDE + (ww)[j] * LDS_STRIDE + (k0c)); \
}

// consume stage (sum+relu) while REISSUING each slot with NEXT ITER's tokens
#define SUM_REISSUE(aout, g, qq, ww, k0c) { \
    half8 s_ = (g)[8]; \
    (g)[8] = *(const half8*)(T_lds + (qq) * LDS_STRIDE + (k0c)); \
    _Pragma("unroll") \
    for (int j = 0; j < NW; ++j) { \
        s_ += (g)[j]; \
        (g)[j] = *(const half8*)(T_lds + NTOK * LDS_STRIDE + (ww)[j] * LDS_STRIDE + (k0c)); \
    } \
    half8 z_ = (half8)(_Float16)0; \
    aout = __builtin_elementwise_max(s_, z_); \
}

// final consume, no reissue
#define SUM_FINAL(aout, g) { \
    half8 s_ = (g)[8]; \
    _Pragma("unroll") \
    for (int j = 0; j < NW; ++j) s_ += (g)[j]; \
    half8 z_ = (half8)(_Float16)0; \
    aout = __builtin_elementwise_max(s_, z_); \
}

// first K-half of the MFMAs (C init = bias)
#define MFMA_K0 { \
    _Pragma("unroll") \
    for (int nt = 0; nt < 4; ++nt) \
        acc4[nt] = __builtin_amdgcn_mfma_f32_16x16x32_f16(wfrag[nt][0], a0, b2v[nt], 0, 0, 0); \
}

// second K-half + stores
#define MFMA_K1_ST(t_) { \
    float* op = out + (size_t)(row0 + (t_) * ROWS_PER_ITER) * HID; \
    _Pragma("unroll") \
    for (int nt = 0; nt < 4; ++nt) { \
        acc4[nt] = __builtin_amdgcn_mfma_f32_16x16x32_f16(wfrag[nt][1], a1, acc4[nt], 0, 0, 0); \
        *(float4v*)(op + nt * 16 + lg * 4) = acc4[nt]; \
    } \
}

// iter t: consume stages (pre-filled with t's tokens), reissue with t+1's
// (N) tokens, then prefetch tokens for t+2 into C's (now dead) slots.
#define ITER_MID(C, N, t_) { \
    SUM_REISSUE(a0, g0, q##N, w##N, lk8); \
    MFMA_K0; \
    SUM_REISSUE(a1, g1, q##N, w##N, 32 + lk8); \
    MFMA_K1_ST(t_); \
    LOADT(C, (t_) + 2); \
}
#define ITER_NOLOAD(C, N, t_) { \
    SUM_REISSUE(a0, g0, q##N, w##N, lk8); \
    MFMA_K0; \
    SUM_REISSUE(a1, g1, q##N, w##N, 32 + lk8); \
    MFMA_K1_ST(t_); \
}
#define ITER_LAST(t_) { \
    SUM_FINAL(a0, g0); \
    MFMA_K0; \
    SUM_FINAL(a1, g1); \
    MFMA_K1_ST(t_); \
}

    // ---- (1) iter 0/1 token loads: HBM latency hides under W2+fill+barrier ----
    LOADT(A, 0);
    LOADT(B, 1);

    // ---- (2) W2 A-fragments in registers (whole 64x64, f16) + b2 float4 ----
    half8   wfrag[4][2];
    float4v b2v[4];
#pragma unroll
    for (int nt = 0; nt < 4; ++nt) {
        b2v[nt] = *(const float4v*)(b2 + nt * 16 + lg * 4);
#pragma unroll
        for (int kc = 0; kc < 2; ++kc) {
            const float* wp = W2 + (nt * 16 + lrow) * HID + kc * 32 + lk8;
            half8 f;
#pragma unroll
            for (int j = 0; j < 8; ++j) f[j] = (_Float16)wp[j];
            wfrag[nt][kc] = f;
        }
    }

    // ---- (3) fill LDS tables (16B chunks; row stride 144B) ----
    for (int i = tid; i < 2 * NTOK * (HID / 8); i += BLOCK) {
        int tbi = i / (NTOK * 8);
        int rem = i - tbi * (NTOK * 8);
        int t   = rem >> 3;
        int kq  = (rem & 7) << 3;
        *(ushort8v*)(T_lds + tbi * (NTOK * LDS_STRIDE) + t * LDS_STRIDE + kq) =
            *(const ushort8v*)(tbl + tbi * (NTOK * HID) + t * HID + kq);
    }
    __syncthreads();

    // ---- (4) depth-2 pipeline over 16 iterations (all indices static) ----
    GATHER_ALL(g0, qA, wA, lk8);        // iter0 chunk0
    GATHER_ALL(g1, qA, wA, 32 + lk8);   // iter0 chunk1

    ITER_MID(A, B, 0);
    ITER_MID(B, A, 1);
    ITER_MID(A, B, 2);
    ITER_MID(B, A, 3);
    ITER_MID(A, B, 4);
    ITER_MID(B, A, 5);
    ITER_MID(A, B, 6);
    ITER_MID(B, A, 7);
    ITER_MID(A, B, 8);
    ITER_MID(B, A, 9);
    ITER_MID(A, B, 10);
    ITER_MID(B, A, 11);
    ITER_MID(A, B, 12);
    ITER_MID(B, A, 13);
    ITER_NOLOAD(A, B, 14);  // consume A(14), reissue B(15)
    ITER_LAST(15);          // consume B(15)

#undef LOADT
#undef GATHER_ALL
#undef SUM_REISSUE
#undef SUM_FINAL
#undef MFMA_K0
#undef MFMA_K1_ST
#undef ITER_MID
#undef ITER_NOLOAD
#undef ITER_LAST
}

extern "C" void kernel_launch(void* const* d_in, const int* in_sizes, int n_in,
                              void* d_out, int out_size, void* d_ws, size_t ws_size,
                              hipStream_t stream) {
    const int*   seqs  = (const int*)d_in[0];
    const int*   qtok  = (const int*)d_in[1];
    const float* embed = (const float*)d_in[2];
    const float* W1    = (const float*)d_in[3];
    const float* b1    = (const float*)d_in[4];
    const float* W2    = (const float*)d_in[5];
    const float* b2    = (const float*)d_in[6];
    float* out = (float*)d_out;
    unsigned short* tbl = (unsigned short*)d_ws;

    int B = in_sizes[0] / SEQ;

    build_tables<<<NTOK * 2, HID, 0, stream>>>(embed, W1, b1, tbl);

    int grid = B / (ITERS * ROWS_PER_ITER);
    fused_forward<<<grid, BLOCK, 0, stream>>>(seqs, qtok, W2, b2, tbl, out);
}